// Round 10
// baseline (258.903 us; speedup 1.0000x reference)
//
#include <hip/hip_runtime.h>

typedef unsigned short u16;
typedef unsigned int u32;
typedef unsigned long long u64;
typedef __attribute__((ext_vector_type(8))) short bfrag;  // 8 bf16 (4 VGPRs)
typedef __attribute__((ext_vector_type(4))) short sfrag;  // 4 bf16 (2 VGPRs)
typedef __attribute__((ext_vector_type(4))) float ffrag;  // 4 fp32

// B=256, L=200, D=256, H=16, Dh=16, M=51200
// Head-major slice: [B,H,L,16], slice stride 3200 u16, b-stride 51200 u16.

__device__ __forceinline__ float bf2f(u16 u) {
    union { float f; u32 i; } c; c.i = ((u32)u) << 16; return c.f;
}
__device__ __forceinline__ u16 f2bf(float f) {           // RNE
    union { float f; u32 i; } c; c.f = f;
    u32 r = c.i + 0x7FFFu + ((c.i >> 16) & 1u);
    return (u16)(r >> 16);
}
__device__ __forceinline__ u32 pack2bf(float lo, float hi) {  // RNE pair
    union { float f; u32 i; } a, b; a.f = lo; b.f = hi;
    u32 ra = a.i + 0x7FFFu + ((a.i >> 16) & 1u);
    u32 rb = b.i + 0x7FFFu + ((b.i >> 16) & 1u);
    return (ra >> 16) | (rb & 0xFFFF0000u);
}
__device__ __forceinline__ ffrag mfma16(bfrag a, bfrag b, ffrag c) {
    return __builtin_amdgcn_mfma_f32_16x16x32_bf16(a, b, c, 0, 0, 0);
}
__device__ __forceinline__ ffrag mfma16k16(sfrag a, sfrag b, ffrag c) {
    return __builtin_amdgcn_mfma_f32_16x16x16bf16_1k(a, b, c, 0, 0, 0);
}

// ---------------------------------------------------------------------------
// LDS-tiled transpose+cast: W[k][n] f32 -> Wt[n][k] bf16, 4 matrices.
// ---------------------------------------------------------------------------
__global__ __launch_bounds__(256) void wtrans_k(
    const float* __restrict__ W0, const float* __restrict__ W1,
    const float* __restrict__ W2, const float* __restrict__ W3,
    u16* __restrict__ Wt)
{
    __shared__ u16 t_s[64][72];
    const int mat = blockIdx.z;
    const float* W = (mat == 0) ? W0 : (mat == 1) ? W1 : (mat == 2) ? W2 : W3;
    const int k0 = blockIdx.x * 64, n0 = blockIdx.y * 64;
    const int r = threadIdx.x >> 2, cq = threadIdx.x & 3;

    const float* src = W + (size_t)(k0 + r) * 256 + n0 + cq * 16;
#pragma unroll
    for (int j = 0; j < 16; j += 4) {
        float4 f = *(const float4*)(src + j);
        t_s[cq * 16 + j + 0][r] = f2bf(f.x);
        t_s[cq * 16 + j + 1][r] = f2bf(f.y);
        t_s[cq * 16 + j + 2][r] = f2bf(f.z);
        t_s[cq * 16 + j + 3][r] = f2bf(f.w);
    }
    __syncthreads();
    u16* dst = Wt + ((size_t)mat * 256 + n0 + r) * 256 + k0 + cq * 16;
    *(bfrag*)(dst)     = *(const bfrag*)&t_s[r][cq * 16];
    *(bfrag*)(dst + 8) = *(const bfrag*)&t_s[r][cq * 16 + 8];
}

// ---------------------------------------------------------------------------
// Barrier-free GEMM: C[m-tile 64, N] = A @ Wt^T + bias.
// A panel (64x256 bf16, plane-major [k-chunk 8][row][8]) staged to LDS ONCE
// (single __syncthreads in the kernel); B fragments stream directly from
// global Wt (512 KB total -> L2-resident). No K-loop barriers at all —
// kills the per-iter vmcnt-drain and the 4.9M/dispatch staging conflicts,
// and X is fetched from HBM exactly once (no n-tile re-read).
// QKV=true : A = X f32 l-major, N=768 (wave w: n = w*192 + ns*64, ns<3),
//            writes Q/K/V head-major bf16.
// QKV=false: A = ctx bf16 head-major, N=256 (wave w: n = w*64),
//            writes news_out l-major bf16.
// grid 800, block 256.
// ---------------------------------------------------------------------------
template<bool QKV>
__global__ __launch_bounds__(256) void gemmL2_k(
    const void* __restrict__ Avp, const u16* __restrict__ Wtp,
    const float* __restrict__ b0, const float* __restrict__ b1,
    const float* __restrict__ b2,
    u16* __restrict__ o0, u16* __restrict__ o1, u16* __restrict__ o2)
{
    const int m0 = blockIdx.x * 64;
    const int tid = threadIdx.x;
    const int wave = tid >> 6, lane = tid & 63;
    const int quad = lane >> 4, l16 = lane & 15;

    __shared__ __align__(16) u16 a_s[32][64][8];   // 32 KB; plane p = k 8p..8p+7

    if constexpr (QKV) {
        const float* Af = (const float*)Avp;
        const int rsub = tid & 3, q4 = tid >> 2;   // k = q4*4
        const int plane = q4 >> 1, cofs = (q4 & 1) * 4;
        const int sw = (plane & 3) << 2;
#pragma unroll
        for (int it = 0; it < 16; it++) {
            int row = it * 4 + rsub;
            float4 f = *(const float4*)(Af + (size_t)(m0 + row) * 256 + q4 * 4);
            u32* d = (u32*)&a_s[plane][row ^ sw][cofs];
            d[0] = pack2bf(f.x, f.y);
            d[1] = pack2bf(f.z, f.w);
        }
    } else {
        const u16* Ab = (const u16*)Avp;
        const int q = tid & 31, rbase = tid >> 5;  // k = q*8
        const size_t hofs = (size_t)(q >> 1) * 3200 + (q & 1) * 8;
        const int sw = (q & 3) << 2;
#pragma unroll
        for (int it = 0; it < 8; it++) {
            int row = it * 8 + rbase;
            int gr = m0 + row;
            unsigned bb = (unsigned)gr / 200u, ll = gr - bb * 200u;
            *(bfrag*)&a_s[q][row ^ sw][0] =
                *(const bfrag*)(Ab + (size_t)bb * 51200 + ll * 16 + hofs);
        }
    }
    __syncthreads();

    const int NS = QKV ? 3 : 1;
    for (int ns = 0; ns < NS; ns++) {
        const int n0 = QKV ? (wave * 192 + ns * 64) : (wave * 64);
        ffrag acc[4][4];
        ffrag zf = {0.f, 0.f, 0.f, 0.f};
#pragma unroll
        for (int mi = 0; mi < 4; mi++)
#pragma unroll
            for (int ni = 0; ni < 4; ni++) acc[mi][ni] = zf;

        const u16* bW = Wtp + (size_t)(n0 + l16) * 256 + quad * 8;
#pragma unroll
        for (int k5 = 0; k5 < 8; k5++) {
            const int p = k5 * 4 + quad;            // p&3 == quad
            bfrag af[4], bf[4];
#pragma unroll
            for (int mi = 0; mi < 4; mi++)
                af[mi] = *(const bfrag*)&a_s[p][(mi * 16 + l16) ^ (quad << 2)][0];
#pragma unroll
            for (int ni = 0; ni < 4; ni++)
                bf[ni] = *(const bfrag*)(bW + ni * 4096 + k5 * 32);
#pragma unroll
            for (int mi = 0; mi < 4; mi++)
#pragma unroll
                for (int ni = 0; ni < 4; ni++)
                    acc[mi][ni] = mfma16(af[mi], bf[ni], acc[mi][ni]);
        }

        if constexpr (QKV) {
            const int mat = n0 >> 8;               // subtile lies in one matrix
            const float* bias = (mat == 0) ? b0 : (mat == 1) ? b1 : b2;
            u16* dst = (mat == 0) ? o0 : (mat == 1) ? o1 : o2;
#pragma unroll
            for (int ni = 0; ni < 4; ni++) {
                int nloc = (n0 & 255) + ni * 16 + l16;
                float bb = bias[nloc];
                size_t hbase = (size_t)(nloc >> 4) * 3200 + (nloc & 15);
#pragma unroll
                for (int mi = 0; mi < 4; mi++) {
                    int rowb = m0 + mi * 16 + quad * 4;
#pragma unroll
                    for (int r = 0; r < 4; r++) {
                        unsigned row = rowb + r;
                        unsigned bb_ = row / 200u, ll = row - bb_ * 200u;
                        dst[(size_t)bb_ * 51200 + hbase + ll * 16] =
                            f2bf(acc[mi][ni][r] + bb);
                    }
                }
            }
        } else {
#pragma unroll
            for (int ni = 0; ni < 4; ni++) {
                int col = n0 + ni * 16 + l16;
                float bb = b0[col];
#pragma unroll
                for (int mi = 0; mi < 4; mi++) {
                    int rowb = m0 + mi * 16 + quad * 4;
#pragma unroll
                    for (int r = 0; r < 4; r++)
                        o0[(size_t)(rowb + r) * 256 + col] =
                            f2bf(acc[mi][ni][r] + bb);
                }
            }
        }
    }
}

// ---------------------------------------------------------------------------
// MHA per (b,h), KEY-COMPACTED (r9, unchanged). grid 4096, block 256.
// ---------------------------------------------------------------------------
__global__ __launch_bounds__(256) void attn_k(
    u16* __restrict__ Q, const u16* __restrict__ K,
    const u16* __restrict__ V, const int* __restrict__ msk)
{
    const int blk = blockIdx.x;            // b*16+h
    const int b = blk >> 4;
    const int tid = threadIdx.x;
    const int wave = tid >> 6, lane = tid & 63;
    const int quad = lane >> 4, l16 = lane & 15;
    const size_t sbase = (size_t)blk * 3200;

    const float SL2E = 0.36067376022224085f;   // 0.25 * log2(e)

    __shared__ __align__(8)  u16 kc_s[208][20];
    __shared__ __align__(16) u16 vt_s[16][228];
    __shared__ __align__(16) float am_s[224];
    __shared__ u16 idx_s[208];
    __shared__ int wcnt_s[4];

    int m = 0;
    if (tid < 200) m = (msk[b * 200 + tid] != 0) ? 1 : 0;
    u64 bal = __ballot(m);
    if (lane == 0) wcnt_s[wave] = __popcll(bal);
    if (tid < 208) {
        u64* z = (u64*)&kc_s[tid][0];
        z[0] = 0; z[1] = 0; z[2] = 0; z[3] = 0;
    }
    u32* vz = (u32*)&vt_s[0][0];
    for (int i = tid; i < 1824; i += 256) vz[i] = 0;
    __syncthreads();

    int cnt = wcnt_s[0] + wcnt_s[1] + wcnt_s[2] + wcnt_s[3];
    if (cnt == 0) {                       // all masked -> uniform (== reference)
        if (tid < 200) idx_s[tid] = (u16)tid;
        cnt = 200;
    } else if (m) {
        int woff = (wave > 0 ? wcnt_s[0] : 0) + (wave > 1 ? wcnt_s[1] : 0)
                 + (wave > 2 ? wcnt_s[2] : 0);
        idx_s[woff + __popcll(bal & ((1ull << lane) - 1ull))] = (u16)tid;
    }
    for (int i = tid; i < 224; i += 256)
        am_s[i] = (i < cnt) ? 0.f : -1e30f;
    __syncthreads();

    if (tid < cnt) {
        int row = idx_s[tid];
        const u64* ks = (const u64*)(K + sbase + row * 16);
        u64* kd = (u64*)&kc_s[tid][0];
        kd[0] = ks[0]; kd[1] = ks[1]; kd[2] = ks[2]; kd[3] = ks[3];
        const u16* vp = V + sbase + row * 16;
        bfrag v0 = *(const bfrag*)vp;
        bfrag v1 = *(const bfrag*)(vp + 8);
#pragma unroll
        for (int j = 0; j < 8; j++) {
            vt_s[j][tid]     = (u16)v0[j];
            vt_s[8 + j][tid] = (u16)v1[j];
        }
    }
    __syncthreads();

    const int nt = (cnt + 15) >> 4;

    for (int t = wave; t < 13; t += 4) {
        int lq = t * 16 + l16; if (lq > 199) lq = 199;
        sfrag qf = *(const sfrag*)(Q + sbase + lq * 16 + quad * 4);

        float s[13][4];
#pragma unroll
        for (int kt = 0; kt < 13; kt++) {
            if (kt < nt) {
                sfrag kf = *(const sfrag*)&kc_s[kt * 16 + l16][quad * 4];
                ffrag c = {0.f, 0.f, 0.f, 0.f};
                c = mfma16k16(kf, qf, c);
                ffrag am4 = *(const ffrag*)&am_s[kt * 16 + quad * 4];
#pragma unroll
                for (int r = 0; r < 4; r++)
                    s[kt][r] = __builtin_fmaf(c[r], SL2E, am4[r]);
            }
        }
        float mx = -3e38f;
#pragma unroll
        for (int kt = 0; kt < 13; kt++)
            if (kt < nt)
#pragma unroll
                for (int r = 0; r < 4; r++) mx = fmaxf(mx, s[kt][r]);
        mx = fmaxf(mx, __shfl_xor(mx, 16, 64));
        mx = fmaxf(mx, __shfl_xor(mx, 32, 64));
        float sm = 0.f;
#pragma unroll
        for (int kt = 0; kt < 13; kt++) {
            if (kt < nt) {
                float p0 = __builtin_amdgcn_exp2f(s[kt][0] - mx);
                float p1 = __builtin_amdgcn_exp2f(s[kt][1] - mx);
                float p2 = __builtin_amdgcn_exp2f(s[kt][2] - mx);
                float p3 = __builtin_amdgcn_exp2f(s[kt][3] - mx);
                sm += (p0 + p1) + (p2 + p3);
                s[kt][0] = p0; s[kt][1] = p1; s[kt][2] = p2; s[kt][3] = p3;
            }
        }
        sm += __shfl_xor(sm, 16, 64);
        sm += __shfl_xor(sm, 32, 64);
        float rs = 1.0f / sm;
        ffrag o = {0.f, 0.f, 0.f, 0.f};
#pragma unroll
        for (int kt = 0; kt < 13; kt++) {
            if (kt < nt) {
                union { sfrag v; u32 u[2]; } pk;
                pk.u[0] = pack2bf(s[kt][0] * rs, s[kt][1] * rs);
                pk.u[1] = pack2bf(s[kt][2] * rs, s[kt][3] * rs);
                sfrag bv = *(const sfrag*)&vt_s[l16][kt * 16 + quad * 4];
                o = mfma16k16(pk.v, bv, o);
            }
        }
        int lb = t * 16 + quad * 4;
        u16* qo = Q + sbase + lb * 16 + l16;
#pragma unroll
        for (int r = 0; r < 4; r++) {
            if (lb + r < 200)
                qo[r * 16] = f2bf(o[r]);   // ctx in-place over Q
        }
    }
}

// ---------------------------------------------------------------------------
// Query pooling per batch (r9, unchanged). grid 256, block 512. f32 out.
// ---------------------------------------------------------------------------
__global__ __launch_bounds__(512) void pool_k(
    const u16* __restrict__ NO, const int* __restrict__ msk,
    const float* __restrict__ qn, float* __restrict__ out)
{
    const int b = blockIdx.x;
    const int tid = threadIdx.x;
    const int wave = tid >> 6, lane = tid & 63;

    __shared__ float q_sh[256];
    __shared__ float s_sh[200];
    __shared__ float p_sh[200];
    __shared__ float red_s[16];
    __shared__ float part_s[8][256];

    if (tid < 256) q_sh[tid] = qn[tid];
    __syncthreads();

    const u16* base = NO + (size_t)b * 51200;

    for (int rr = 0; rr < 25; rr++) {
        int l = wave * 25 + rr;
        u64 v = *(const u64*)(base + l * 256 + lane * 4);
        float d = bf2f((u16)v)         * q_sh[lane * 4 + 0]
                + bf2f((u16)(v >> 16)) * q_sh[lane * 4 + 1]
                + bf2f((u16)(v >> 32)) * q_sh[lane * 4 + 2]
                + bf2f((u16)(v >> 48)) * q_sh[lane * 4 + 3];
#pragma unroll
        for (int dd = 1; dd < 64; dd <<= 1) d += __shfl_xor(d, dd, 64);
        if (lane == 0) s_sh[l] = d * 0.0625f;
    }
    __syncthreads();

    float s = -1e30f;
    if (tid < 200) s = msk[b * 200 + tid] ? s_sh[tid] : -1e9f;
    float mw = s;
#pragma unroll
    for (int dd = 1; dd < 64; dd <<= 1) mw = fmaxf(mw, __shfl_xor(mw, dd, 64));
    if (lane == 0) red_s[wave] = mw;
    __syncthreads();
    float mmax = red_s[0];
#pragma unroll
    for (int w = 1; w < 8; w++) mmax = fmaxf(mmax, red_s[w]);
    float e = (tid < 200) ? __expf(s - mmax) : 0.f;
    float sw = e;
#pragma unroll
    for (int dd = 1; dd < 64; dd <<= 1) sw += __shfl_xor(sw, dd, 64);
    if (lane == 0) red_s[8 + wave] = sw;
    __syncthreads();
    float ssum = 0.f;
#pragma unroll
    for (int w = 0; w < 8; w++) ssum += red_s[8 + w];
    if (tid < 200) p_sh[tid] = e / ssum;
    __syncthreads();

    float a0 = 0.f, a1 = 0.f, a2 = 0.f, a3 = 0.f;
    for (int rr = 0; rr < 25; rr++) {
        int l = wave * 25 + rr;
        float p = p_sh[l];
        u64 v = *(const u64*)(base + l * 256 + lane * 4);
        a0 += p * bf2f((u16)v);
        a1 += p * bf2f((u16)(v >> 16));
        a2 += p * bf2f((u16)(v >> 32));
        a3 += p * bf2f((u16)(v >> 48));
    }
    part_s[wave][lane * 4 + 0] = a0;
    part_s[wave][lane * 4 + 1] = a1;
    part_s[wave][lane * 4 + 2] = a2;
    part_s[wave][lane * 4 + 3] = a3;
    __syncthreads();
    if (tid < 256) {
        float t = 0.f;
#pragma unroll
        for (int w = 0; w < 8; w++) t += part_s[w][tid];
        out[(size_t)b * 256 + tid] = t;
    }
}

// ---------------------------------------------------------------------------
extern "C" void kernel_launch(void* const* d_in, const int* in_sizes, int n_in,
                              void* d_out, int out_size, void* d_ws, size_t ws_size,
                              hipStream_t stream) {
    const float* X   = (const float*)d_in[0];
    const int*   msk = (const int*)d_in[1];
    const float* Wq  = (const float*)d_in[2];
    const float* bq  = (const float*)d_in[3];
    const float* Wk  = (const float*)d_in[4];
    const float* bk  = (const float*)d_in[5];
    const float* Wv  = (const float*)d_in[6];
    const float* bv  = (const float*)d_in[7];
    const float* Wo  = (const float*)d_in[8];
    const float* bo  = (const float*)d_in[9];
    const float* qn  = (const float*)d_in[10];
    float* out = (float*)d_out;

    // ws layout (79,167,488 B):
    //   qbuf: Q head-major -> ctx in-place     26,214,400
    //   kbuf: K head-major -> news_out l-major 26,214,400
    //   vbuf: V head-major                     26,214,400
    //   wt:   [1024][256] bf16 weights^T          524,288
    char* ws = (char*)d_ws;
    u16* qbuf = (u16*)(ws);
    u16* kbuf = (u16*)(ws + 26214400);
    u16* vbuf = (u16*)(ws + 52428800);
    u16* wt   = (u16*)(ws + 78643200);

    wtrans_k<<<dim3(4, 4, 4), 256, 0, stream>>>(Wq, Wk, Wv, Wo, wt);

    gemmL2_k<true><<<800, 256, 0, stream>>>(
        X, wt, bq, bk, bv, qbuf, kbuf, vbuf);

    attn_k<<<4096, 256, 0, stream>>>(qbuf, kbuf, vbuf, msk);

    gemmL2_k<false><<<800, 256, 0, stream>>>(
        qbuf, wt + 196608, bo, nullptr, nullptr, kbuf, nullptr, nullptr);

    pool_k<<<256, 512, 0, stream>>>(kbuf, msk, qn, out);
}

// Round 12
// 247.511 us; speedup vs baseline: 1.0460x; 1.0460x over previous
//
#include <hip/hip_runtime.h>

typedef unsigned short u16;
typedef unsigned int u32;
typedef unsigned long long u64;
typedef __attribute__((ext_vector_type(8))) short bfrag;  // 8 bf16 (4 VGPRs)
typedef __attribute__((ext_vector_type(4))) short sfrag;  // 4 bf16 (2 VGPRs)
typedef __attribute__((ext_vector_type(4))) float ffrag;  // 4 fp32

// B=256, L=200, D=256, H=16, Dh=16, M=51200
// Head-major slice: [B,H,L,16], slice stride 3200 u16, b-stride 51200 u16.

__device__ __forceinline__ float bf2f(u16 u) {
    union { float f; u32 i; } c; c.i = ((u32)u) << 16; return c.f;
}
__device__ __forceinline__ u16 f2bf(float f) {           // RNE (software)
    union { float f; u32 i; } c; c.f = f;
    u32 r = c.i + 0x7FFFu + ((c.i >> 16) & 1u);
    return (u16)(r >> 16);
}
// software RNE pair pack (r9-proven). NOTE: r11's v_cvt_pk_bf16_f32 inline
// asm produced NaNs on gfx950 — instruction not in the ISA reference; banned.
__device__ __forceinline__ u32 pack2bf(float lo, float hi) {
    union { float f; u32 i; } a, b; a.f = lo; b.f = hi;
    u32 ra = a.i + 0x7FFFu + ((a.i >> 16) & 1u);
    u32 rb = b.i + 0x7FFFu + ((b.i >> 16) & 1u);
    return (ra >> 16) | (rb & 0xFFFF0000u);
}
__device__ __forceinline__ ffrag mfma16(bfrag a, bfrag b, ffrag c) {
    return __builtin_amdgcn_mfma_f32_16x16x32_bf16(a, b, c, 0, 0, 0);
}
__device__ __forceinline__ ffrag mfma16k16(sfrag a, sfrag b, ffrag c) {
    return __builtin_amdgcn_mfma_f32_16x16x16bf16_1k(a, b, c, 0, 0, 0);
}

// ---------------------------------------------------------------------------
// LDS-tiled transpose+cast: W[k][n] f32 -> Wt[n][k] bf16, 4 matrices.
// ---------------------------------------------------------------------------
__global__ __launch_bounds__(256) void wtrans_k(
    const float* __restrict__ W0, const float* __restrict__ W1,
    const float* __restrict__ W2, const float* __restrict__ W3,
    u16* __restrict__ Wt)
{
    __shared__ u16 t_s[64][72];
    const int mat = blockIdx.z;
    const float* W = (mat == 0) ? W0 : (mat == 1) ? W1 : (mat == 2) ? W2 : W3;
    const int k0 = blockIdx.x * 64, n0 = blockIdx.y * 64;
    const int r = threadIdx.x >> 2, cq = threadIdx.x & 3;

    const float* src = W + (size_t)(k0 + r) * 256 + n0 + cq * 16;
#pragma unroll
    for (int j = 0; j < 16; j += 4) {
        float4 f = *(const float4*)(src + j);
        t_s[cq * 16 + j + 0][r] = f2bf(f.x);
        t_s[cq * 16 + j + 1][r] = f2bf(f.y);
        t_s[cq * 16 + j + 2][r] = f2bf(f.z);
        t_s[cq * 16 + j + 3][r] = f2bf(f.w);
    }
    __syncthreads();
    u16* dst = Wt + ((size_t)mat * 256 + n0 + r) * 256 + k0 + cq * 16;
    *(bfrag*)(dst)     = *(const bfrag*)&t_s[r][cq * 16];
    *(bfrag*)(dst + 8) = *(const bfrag*)&t_s[r][cq * 16 + 8];
}

// ---------------------------------------------------------------------------
// GEMM (r9 structure + hoisted epilogue + L2 swizzle): C = A @ Wt^T + bias.
// Grid (n-tiles, m-tiles), n FASTEST: consecutive blocks share one A-tile.
// QKV=true : A = X (f32 l-major), grid (6,400), writes Q/K/V head-major bf16.
// QKV=false: A = ctx (bf16 head-major), grid (2,400), writes l-major bf16.
// block tile 128x128, wave tile 64x64, BK=32, XOR-swizzled LDS.
// ---------------------------------------------------------------------------
template<bool QKV>
__global__ __launch_bounds__(256) void gemm_k(
    const void* __restrict__ Avp, const u16* __restrict__ Wtp,
    const float* __restrict__ b0, const float* __restrict__ b1,
    const float* __restrict__ b2,
    u16* __restrict__ o0, u16* __restrict__ o1, u16* __restrict__ o2)
{
    const int nblk = blockIdx.x;            // n-tile (fastest)
    const int m0 = blockIdx.y * 128;
    const int n0g = nblk * 128;
    const int tid = threadIdx.x;
    const int wave = tid >> 6, lane = tid & 63;
    const int quad = lane >> 4, l16 = lane & 15;
    const int wm = wave >> 1, wn = wave & 1;

    __shared__ __align__(16) u16 a_s[4][128][8];
    __shared__ __align__(16) u16 b_s[4][128][8];

    ffrag zf = {0.f, 0.f, 0.f, 0.f};
    ffrag acc[4][4];
#pragma unroll
    for (int mi = 0; mi < 4; mi++)
#pragma unroll
        for (int ni = 0; ni < 4; ni++) acc[mi][ni] = zf;

    const int sr = tid >> 2;
    const int sc = tid & 3;
    const float* Af = (const float*)Avp;
    const u16*   Ab = (const u16*)Avp;
    const u16* Wp = Wtp + (size_t)(n0g + sr) * 256 + sc * 8;

    int r0 = m0 + sr, r1 = r0 + 64;
    unsigned bA0 = (unsigned)r0 / 200u, bA1 = (unsigned)r1 / 200u;
    size_t base0 = (size_t)bA0 * 51200 + (r0 - bA0 * 200) * 16;
    size_t base1 = (size_t)bA1 * 51200 + (r1 - bA1 * 200) * 16;

    for (int kk = 0; kk < 256; kk += 32) {
        __syncthreads();
        if constexpr (QKV) {
            const float* p0 = Af + (size_t)r0 * 256 + sc * 8 + kk;
            const float* p1 = Af + (size_t)r1 * 256 + sc * 8 + kk;
            float4 f0 = *(const float4*)p0, f1 = *(const float4*)(p0 + 4);
            float4 g0 = *(const float4*)p1, g1 = *(const float4*)(p1 + 4);
            uint4 va = { pack2bf(f0.x, f0.y), pack2bf(f0.z, f0.w),
                         pack2bf(f1.x, f1.y), pack2bf(f1.z, f1.w) };
            uint4 vb = { pack2bf(g0.x, g0.y), pack2bf(g0.z, g0.w),
                         pack2bf(g1.x, g1.y), pack2bf(g1.z, g1.w) };
            *(uint4*)&a_s[sc][sr        ^ (sc << 2)][0] = va;
            *(uint4*)&a_s[sc][(sr + 64) ^ (sc << 2)][0] = vb;
        } else {
            int c = kk + sc * 8;
            size_t hofs = (size_t)(c >> 4) * 3200 + (c & 8);
            *(bfrag*)&a_s[sc][sr        ^ (sc << 2)][0] = *(const bfrag*)(Ab + base0 + hofs);
            *(bfrag*)&a_s[sc][(sr + 64) ^ (sc << 2)][0] = *(const bfrag*)(Ab + base1 + hofs);
        }
        *(bfrag*)&b_s[sc][sr        ^ (sc << 2)][0] = *(const bfrag*)(Wp + kk);
        *(bfrag*)&b_s[sc][(sr + 64) ^ (sc << 2)][0] = *(const bfrag*)(Wp + (size_t)64 * 256 + kk);
        __syncthreads();

        bfrag af[4], bfr[4];
#pragma unroll
        for (int mi = 0; mi < 4; mi++) {
            int m = wm * 64 + mi * 16 + l16;
            af[mi] = *(const bfrag*)&a_s[quad][m ^ (quad << 2)][0];
        }
#pragma unroll
        for (int ni = 0; ni < 4; ni++) {
            int n = wn * 64 + ni * 16 + l16;
            bfr[ni] = *(const bfrag*)&b_s[quad][n ^ (quad << 2)][0];
        }
#pragma unroll
        for (int mi = 0; mi < 4; mi++)
#pragma unroll
            for (int ni = 0; ni < 4; ni++)
                acc[mi][ni] = mfma16(af[mi], bfr[ni], acc[mi][ni]);
    }

    if constexpr (QKV) {
        const float* bias = (nblk < 2) ? b0 : (nblk < 4) ? b1 : b2;
        u16* dst = (nblk < 2) ? o0 : (nblk < 4) ? o1 : o2;
        // hoisted head-major row offsets (u16 units), reused across ni
        u32 rofs[4][4];
#pragma unroll
        for (int mi = 0; mi < 4; mi++) {
            int rowb = m0 + wm * 64 + mi * 16 + quad * 4;
#pragma unroll
            for (int r = 0; r < 4; r++) {
                unsigned row = rowb + r;
                unsigned bb_ = row / 200u, ll = row - bb_ * 200u;
                rofs[mi][r] = bb_ * 51200u + ll * 16u;
            }
        }
#pragma unroll
        for (int ni = 0; ni < 4; ni++) {
            int nloc = (nblk & 1) * 128 + wn * 64 + ni * 16 + l16;
            float bb = bias[nloc];
            u32 hbase = (u32)(nloc >> 4) * 3200u + (u32)(nloc & 15);
#pragma unroll
            for (int mi = 0; mi < 4; mi++) {
                u32 p01 = pack2bf(acc[mi][ni][0] + bb, acc[mi][ni][1] + bb);
                u32 p23 = pack2bf(acc[mi][ni][2] + bb, acc[mi][ni][3] + bb);
                dst[rofs[mi][0] + hbase] = (u16)p01;
                dst[rofs[mi][1] + hbase] = (u16)(p01 >> 16);
                dst[rofs[mi][2] + hbase] = (u16)p23;
                dst[rofs[mi][3] + hbase] = (u16)(p23 >> 16);
            }
        }
    } else {
#pragma unroll
        for (int ni = 0; ni < 4; ni++) {
            int col = n0g + wn * 64 + ni * 16 + l16;
            float bb = b0[col];
#pragma unroll
            for (int mi = 0; mi < 4; mi++) {
                int rowb = m0 + wm * 64 + mi * 16 + quad * 4;
                u16* dp = o0 + (size_t)rowb * 256 + col;
                u32 p01 = pack2bf(acc[mi][ni][0] + bb, acc[mi][ni][1] + bb);
                u32 p23 = pack2bf(acc[mi][ni][2] + bb, acc[mi][ni][3] + bb);
                dp[0]   = (u16)p01;
                dp[256] = (u16)(p01 >> 16);
                dp[512] = (u16)p23;
                dp[768] = (u16)(p23 >> 16);
            }
        }
    }
}

// ---------------------------------------------------------------------------
// MHA per (b,h), KEY-COMPACTED (r9 structure, software packs). grid 4096.
// ---------------------------------------------------------------------------
__global__ __launch_bounds__(256) void attn_k(
    u16* __restrict__ Q, const u16* __restrict__ K,
    const u16* __restrict__ V, const int* __restrict__ msk)
{
    const int blk = blockIdx.x;            // b*16+h
    const int b = blk >> 4;
    const int tid = threadIdx.x;
    const int wave = tid >> 6, lane = tid & 63;
    const int quad = lane >> 4, l16 = lane & 15;
    const size_t sbase = (size_t)blk * 3200;

    const float SL2E = 0.36067376022224085f;   // 0.25 * log2(e)

    __shared__ __align__(8)  u16 kc_s[208][20];
    __shared__ __align__(16) u16 vt_s[16][228];
    __shared__ __align__(16) float am_s[224];
    __shared__ u16 idx_s[208];
    __shared__ int wcnt_s[4];

    int m = 0;
    if (tid < 200) m = (msk[b * 200 + tid] != 0) ? 1 : 0;
    u64 bal = __ballot(m);
    if (lane == 0) wcnt_s[wave] = __popcll(bal);
    if (tid < 208) {
        u64* z = (u64*)&kc_s[tid][0];
        z[0] = 0; z[1] = 0; z[2] = 0; z[3] = 0;
    }
    u32* vz = (u32*)&vt_s[0][0];
    for (int i = tid; i < 1824; i += 256) vz[i] = 0;
    __syncthreads();

    int cnt = wcnt_s[0] + wcnt_s[1] + wcnt_s[2] + wcnt_s[3];
    if (cnt == 0) {                       // all masked -> uniform (== reference)
        if (tid < 200) idx_s[tid] = (u16)tid;
        cnt = 200;
    } else if (m) {
        int woff = (wave > 0 ? wcnt_s[0] : 0) + (wave > 1 ? wcnt_s[1] : 0)
                 + (wave > 2 ? wcnt_s[2] : 0);
        idx_s[woff + __popcll(bal & ((1ull << lane) - 1ull))] = (u16)tid;
    }
    for (int i = tid; i < 224; i += 256)
        am_s[i] = (i < cnt) ? 0.f : -1e30f;
    __syncthreads();

    if (tid < cnt) {
        int row = idx_s[tid];
        const u64* ks = (const u64*)(K + sbase + row * 16);
        u64* kd = (u64*)&kc_s[tid][0];
        kd[0] = ks[0]; kd[1] = ks[1]; kd[2] = ks[2]; kd[3] = ks[3];
        const u16* vp = V + sbase + row * 16;
        bfrag v0 = *(const bfrag*)vp;
        bfrag v1 = *(const bfrag*)(vp + 8);
#pragma unroll
        for (int j = 0; j < 8; j++) {
            vt_s[j][tid]     = (u16)v0[j];
            vt_s[8 + j][tid] = (u16)v1[j];
        }
    }
    __syncthreads();

    const int nt = (cnt + 15) >> 4;

    for (int t = wave; t < 13; t += 4) {
        int lq = t * 16 + l16; if (lq > 199) lq = 199;
        sfrag qf = *(const sfrag*)(Q + sbase + lq * 16 + quad * 4);

        float s[13][4];
#pragma unroll
        for (int kt = 0; kt < 13; kt++) {
            if (kt < nt) {
                sfrag kf = *(const sfrag*)&kc_s[kt * 16 + l16][quad * 4];
                ffrag c = {0.f, 0.f, 0.f, 0.f};
                c = mfma16k16(kf, qf, c);
                ffrag am4 = *(const ffrag*)&am_s[kt * 16 + quad * 4];
#pragma unroll
                for (int r = 0; r < 4; r++)
                    s[kt][r] = __builtin_fmaf(c[r], SL2E, am4[r]);
            }
        }
        float mx = -3e38f;
#pragma unroll
        for (int kt = 0; kt < 13; kt++)
            if (kt < nt)
#pragma unroll
                for (int r = 0; r < 4; r++) mx = fmaxf(mx, s[kt][r]);
        mx = fmaxf(mx, __shfl_xor(mx, 16, 64));
        mx = fmaxf(mx, __shfl_xor(mx, 32, 64));
        float sm = 0.f;
#pragma unroll
        for (int kt = 0; kt < 13; kt++) {
            if (kt < nt) {
                float p0 = __builtin_amdgcn_exp2f(s[kt][0] - mx);
                float p1 = __builtin_amdgcn_exp2f(s[kt][1] - mx);
                float p2 = __builtin_amdgcn_exp2f(s[kt][2] - mx);
                float p3 = __builtin_amdgcn_exp2f(s[kt][3] - mx);
                sm += (p0 + p1) + (p2 + p3);
                s[kt][0] = p0; s[kt][1] = p1; s[kt][2] = p2; s[kt][3] = p3;
            }
        }
        sm += __shfl_xor(sm, 16, 64);
        sm += __shfl_xor(sm, 32, 64);
        float rs = 1.0f / sm;
        ffrag o = {0.f, 0.f, 0.f, 0.f};
#pragma unroll
        for (int kt = 0; kt < 13; kt++) {
            if (kt < nt) {
                union { sfrag v; u32 u[2]; } pk;
                pk.u[0] = pack2bf(s[kt][0] * rs, s[kt][1] * rs);
                pk.u[1] = pack2bf(s[kt][2] * rs, s[kt][3] * rs);
                sfrag bv = *(const sfrag*)&vt_s[l16][kt * 16 + quad * 4];
                o = mfma16k16(pk.v, bv, o);
            }
        }
        int lb = t * 16 + quad * 4;
        u16* qo = Q + sbase + lb * 16 + l16;
        u32 o01 = pack2bf(o[0], o[1]);
        u32 o23 = pack2bf(o[2], o[3]);
        if (lb + 0 < 200) qo[0]  = (u16)o01;
        if (lb + 1 < 200) qo[16] = (u16)(o01 >> 16);
        if (lb + 2 < 200) qo[32] = (u16)o23;
        if (lb + 3 < 200) qo[48] = (u16)(o23 >> 16);
    }
}

// ---------------------------------------------------------------------------
// Query pooling per batch (r9, unchanged). grid 256, block 512. f32 out.
// ---------------------------------------------------------------------------
__global__ __launch_bounds__(512) void pool_k(
    const u16* __restrict__ NO, const int* __restrict__ msk,
    const float* __restrict__ qn, float* __restrict__ out)
{
    const int b = blockIdx.x;
    const int tid = threadIdx.x;
    const int wave = tid >> 6, lane = tid & 63;

    __shared__ float q_sh[256];
    __shared__ float s_sh[200];
    __shared__ float p_sh[200];
    __shared__ float red_s[16];
    __shared__ float part_s[8][256];

    if (tid < 256) q_sh[tid] = qn[tid];
    __syncthreads();

    const u16* base = NO + (size_t)b * 51200;

    for (int rr = 0; rr < 25; rr++) {
        int l = wave * 25 + rr;
        u64 v = *(const u64*)(base + l * 256 + lane * 4);
        float d = bf2f((u16)v)         * q_sh[lane * 4 + 0]
                + bf2f((u16)(v >> 16)) * q_sh[lane * 4 + 1]
                + bf2f((u16)(v >> 32)) * q_sh[lane * 4 + 2]
                + bf2f((u16)(v >> 48)) * q_sh[lane * 4 + 3];
#pragma unroll
        for (int dd = 1; dd < 64; dd <<= 1) d += __shfl_xor(d, dd, 64);
        if (lane == 0) s_sh[l] = d * 0.0625f;
    }
    __syncthreads();

    float s = -1e30f;
    if (tid < 200) s = msk[b * 200 + tid] ? s_sh[tid] : -1e9f;
    float mw = s;
#pragma unroll
    for (int dd = 1; dd < 64; dd <<= 1) mw = fmaxf(mw, __shfl_xor(mw, dd, 64));
    if (lane == 0) red_s[wave] = mw;
    __syncthreads();
    float mmax = red_s[0];
#pragma unroll
    for (int w = 1; w < 8; w++) mmax = fmaxf(mmax, red_s[w]);
    float e = (tid < 200) ? __expf(s - mmax) : 0.f;
    float sw = e;
#pragma unroll
    for (int dd = 1; dd < 64; dd <<= 1) sw += __shfl_xor(sw, dd, 64);
    if (lane == 0) red_s[8 + wave] = sw;
    __syncthreads();
    float ssum = 0.f;
#pragma unroll
    for (int w = 0; w < 8; w++) ssum += red_s[8 + w];
    if (tid < 200) p_sh[tid] = e / ssum;
    __syncthreads();

    float a0 = 0.f, a1 = 0.f, a2 = 0.f, a3 = 0.f;
    for (int rr = 0; rr < 25; rr++) {
        int l = wave * 25 + rr;
        float p = p_sh[l];
        u64 v = *(const u64*)(base + l * 256 + lane * 4);
        a0 += p * bf2f((u16)v);
        a1 += p * bf2f((u16)(v >> 16));
        a2 += p * bf2f((u16)(v >> 32));
        a3 += p * bf2f((u16)(v >> 48));
    }
    part_s[wave][lane * 4 + 0] = a0;
    part_s[wave][lane * 4 + 1] = a1;
    part_s[wave][lane * 4 + 2] = a2;
    part_s[wave][lane * 4 + 3] = a3;
    __syncthreads();
    if (tid < 256) {
        float t = 0.f;
#pragma unroll
        for (int w = 0; w < 8; w++) t += part_s[w][tid];
        out[(size_t)b * 256 + tid] = t;
    }
}

// ---------------------------------------------------------------------------
extern "C" void kernel_launch(void* const* d_in, const int* in_sizes, int n_in,
                              void* d_out, int out_size, void* d_ws, size_t ws_size,
                              hipStream_t stream) {
    const float* X   = (const float*)d_in[0];
    const int*   msk = (const int*)d_in[1];
    const float* Wq  = (const float*)d_in[2];
    const float* bq  = (const float*)d_in[3];
    const float* Wk  = (const float*)d_in[4];
    const float* bk  = (const float*)d_in[5];
    const float* Wv  = (const float*)d_in[6];
    const float* bv  = (const float*)d_in[7];
    const float* Wo  = (const float*)d_in[8];
    const float* bo  = (const float*)d_in[9];
    const float* qn  = (const float*)d_in[10];
    float* out = (float*)d_out;

    // ws layout (79,167,488 B):
    //   qbuf: Q head-major -> ctx in-place     26,214,400
    //   kbuf: K head-major -> news_out l-major 26,214,400
    //   vbuf: V head-major                     26,214,400
    //   wt:   [1024][256] bf16 weights^T          524,288
    char* ws = (char*)d_ws;
    u16* qbuf = (u16*)(ws);
    u16* kbuf = (u16*)(ws + 26214400);
    u16* vbuf = (u16*)(ws + 52428800);
    u16* wt   = (u16*)(ws + 78643200);

    wtrans_k<<<dim3(4, 4, 4), 256, 0, stream>>>(Wq, Wk, Wv, Wo, wt);

    // n-tile index FASTEST: consecutive blocks share one A-tile (L2-hot)
    gemm_k<true><<<dim3(6, 400), 256, 0, stream>>>(
        X, wt, bq, bk, bv, qbuf, kbuf, vbuf);

    attn_k<<<4096, 256, 0, stream>>>(qbuf, kbuf, vbuf, msk);

    gemm_k<false><<<dim3(2, 400), 256, 0, stream>>>(
        qbuf, wt + 196608, bo, nullptr, nullptr, kbuf, nullptr, nullptr);

    pool_k<<<256, 512, 0, stream>>>(kbuf, msk, qn, out);
}